// Round 17
// baseline (518.200 us; speedup 1.0000x reference)
//
#include <hip/hip_runtime.h>
#include <math.h>

#define V_WORDS 20000
#define MM 32
#define EE 128
#define HH 4
#define DHH 32
#define NN 8192
#define LL 64
#define CC 128

typedef short bf16x8 __attribute__((ext_vector_type(8)));
typedef float f32x4 __attribute__((ext_vector_type(4)));
typedef unsigned short u16;
typedef unsigned int u32;

__device__ __forceinline__ u16 f2bf(float x) {
    u32 u = __float_as_uint(x);
    u32 r = (u + 0x7FFFu + ((u >> 16) & 1u)) >> 16;
    return (u16)r;
}
__device__ __forceinline__ float bflo(u32 u) { return __uint_as_float(u << 16); }
__device__ __forceinline__ float bfhi(u32 u) { return __uint_as_float(u & 0xFFFF0000u); }

// ---------------------------------------------------------------------------
// Kernel 0: pack conv weights into bf16 MFMA B-fragment order (unchanged).
// ---------------------------------------------------------------------------
__global__ __launch_bounds__(256)
void pack_weights(const float* __restrict__ w3,
                  const float* __restrict__ w4,
                  const float* __restrict__ w5,
                  u16* __restrict__ Bpack)
{
    const int s = blockIdx.x;
    const int t = threadIdx.x;
    const int lane = t & 63;

    const float* src;
    int K, sl;
    if (s < 12)      { src = w3; K = 3; sl = s; }
    else if (s < 28) { src = w4; K = 4; sl = s - 12; }
    else             { src = w5; K = 5; sl = s - 28; }
    const int j  = sl >> 2;
    const int e0 = (sl & 3) * 32;

    for (int nt = (t >> 6); nt < 8; nt += 4) {
        const int c = nt * 16 + (lane & 15);
        const int kb = (lane >> 4) * 8;
        u16 vals[8];
        #pragma unroll
        for (int i = 0; i < 8; ++i) {
            const int e = e0 + kb + i;
            vals[i] = f2bf(src[(c * EE + e) * K + j]);
        }
        u16* dst = Bpack + (((size_t)s * 8 + nt) * 64 + lane) * 8;
        *(bf16x8*)dst = *(const bf16x8*)vals;
    }
}

// ---------------------------------------------------------------------------
// Kernel A (fallback): Kn/Vn projections (unchanged R15 path).
// ---------------------------------------------------------------------------
__global__ __launch_bounds__(256)
void kv_proj_kernel(const float* __restrict__ table,
                    const float* __restrict__ in_w,
                    const float* __restrict__ in_b,
                    u16* __restrict__ Kn16, u16* __restrict__ Vn16)
{
    const int n0 = blockIdx.x * 8;
    const int t = threadIdx.x;
    __shared__ float tbl[8][EE];
    {
        const int r = t >> 5, q4 = (t & 31) * 4;
        *(float4*)&tbl[r][q4] = *(const float4*)&table[(size_t)(n0 + r) * EE + q4];
    }
    __syncthreads();

    const int sel = t >> 7;
    const int i = t & 127;
    const float* w = in_w + (size_t)(sel + 1) * EE * EE + (size_t)i * EE;
    const float bias = in_b[(sel + 1) * EE + i];

    float acc[8];
    #pragma unroll
    for (int r = 0; r < 8; ++r) acc[r] = bias;
    for (int k = 0; k < EE; k += 4) {
        const float4 wv = *(const float4*)&w[k];
        #pragma unroll
        for (int r = 0; r < 8; ++r) {
            acc[r] += tbl[r][k]     * wv.x + tbl[r][k + 1] * wv.y
                    + tbl[r][k + 2] * wv.z + tbl[r][k + 3] * wv.w;
        }
    }
    u16* dst = sel ? Vn16 : Kn16;
    #pragma unroll
    for (int r = 0; r < 8; ++r) dst[(size_t)(n0 + r) * EE + i] = f2bf(acc[r]);
}

// ---------------------------------------------------------------------------
// Kernel A' (R17): Q/K/V projections over the 8192 distinct news rows.
// 384 threads = {Q,K,V} x 128 dims, 8 rows/block. Qn includes bias: since
// the masked mean's weights sum to 1, mean_m(Qn[rows[m]]) == q @ wq^T + bq
// exactly — so word_attn can skip the table gather AND the qh projection.
// ---------------------------------------------------------------------------
__global__ __launch_bounds__(384)
void kvq_proj_kernel(const float* __restrict__ table,
                     const float* __restrict__ in_w,
                     const float* __restrict__ in_b,
                     u16* __restrict__ Qn16,
                     u16* __restrict__ Kn16,
                     u16* __restrict__ Vn16)
{
    const int n0 = blockIdx.x * 8;
    const int t = threadIdx.x;
    __shared__ float tbl[8][EE];
    if (t < 256) {
        const int r = t >> 5, q4 = (t & 31) * 4;
        *(float4*)&tbl[r][q4] = *(const float4*)&table[(size_t)(n0 + r) * EE + q4];
    }
    __syncthreads();

    const int sel = t >> 7;                 // 0 = Q, 1 = K, 2 = V
    const int i = t & 127;
    const float* w = in_w + (size_t)sel * EE * EE + (size_t)i * EE;
    const float bias = in_b[sel * EE + i];

    float acc[8];
    #pragma unroll
    for (int r = 0; r < 8; ++r) acc[r] = bias;
    for (int k = 0; k < EE; k += 4) {
        const float4 wv = *(const float4*)&w[k];
        #pragma unroll
        for (int r = 0; r < 8; ++r) {
            acc[r] += tbl[r][k]     * wv.x + tbl[r][k + 1] * wv.y
                    + tbl[r][k + 2] * wv.z + tbl[r][k + 3] * wv.w;
        }
    }
    u16* dst = (sel == 0) ? Qn16 : (sel == 1) ? Kn16 : Vn16;
    #pragma unroll
    for (int r = 0; r < 8; ++r) dst[(size_t)(n0 + r) * EE + i] = f2bf(acc[r]);
}

// ---------------------------------------------------------------------------
// Kernel B (fallback): per-word attention, R15 path (table-gather + qh proj).
// ---------------------------------------------------------------------------
#define WPB 8
__global__ __launch_bounds__(256, 3)
void word_attn_kernel(const int* __restrict__ word2news,
                      const int* __restrict__ word2news_len,
                      const float* __restrict__ table,
                      const float* __restrict__ in_w,
                      const float* __restrict__ in_b,
                      const float* __restrict__ out_w,
                      const float* __restrict__ out_b,
                      const u16* __restrict__ Kn16,
                      const u16* __restrict__ Vn16,
                      u16* __restrict__ we16)
{
    const int v0 = blockIdx.x * WPB;
    const int t = threadIdx.x;

    __shared__ int   rows[WPB][MM];
    __shared__ int   lenS[WPB];
    __shared__ float q[WPB][EE];
    __shared__ float qh[WPB][EE];
    __shared__ float attn[WPB][HH][MM];
    __shared__ float osh[WPB][EE];

    {
        const int w = t >> 5, m = t & 31;
        rows[w][m] = word2news[(size_t)(v0 + w) * MM + m];
        if (t < WPB) lenS[t] = word2news_len[v0 + t];
    }
    __syncthreads();

    {
        const int w = t >> 5, d0 = (t & 31) * 4;
        const int L = lenS[w];
        float4 a = {0.f, 0.f, 0.f, 0.f};
        #pragma unroll 4
        for (int m = 0; m < MM; ++m) {
            const float4 x = *(const float4*)&table[(size_t)rows[w][m] * EE + d0];
            if (m < L) { a.x += x.x; a.y += x.y; a.z += x.z; a.w += x.w; }
        }
        const float inv = (L > 0) ? 1.0f / (float)L : 0.0f;
        a.x *= inv; a.y *= inv; a.z *= inv; a.w *= inv;
        *(float4*)&q[w][d0] = a;
    }
    __syncthreads();

    {
        const int g = t >> 7, i = t & 127;
        const float* wr = in_w + (size_t)i * EE;
        float acc[4] = {0.f, 0.f, 0.f, 0.f};
        #pragma unroll 4
        for (int k = 0; k < EE; k += 4) {
            const float4 wv = *(const float4*)&wr[k];
            #pragma unroll
            for (int w4 = 0; w4 < 4; ++w4) {
                const float* qw = q[g * 4 + w4];
                acc[w4] += qw[k] * wv.x + qw[k + 1] * wv.y
                         + qw[k + 2] * wv.z + qw[k + 3] * wv.w;
            }
        }
        const float b = in_b[i];
        #pragma unroll
        for (int w4 = 0; w4 < 4; ++w4) qh[g * 4 + w4][i] = acc[w4] + b;
    }
    __syncthreads();

    {
        const int w = t >> 5, m = t & 31;
        const int L = lenS[w];
        float s[HH] = {-1e9f, -1e9f, -1e9f, -1e9f};
        if (m < L) {
            const uint4* kr = (const uint4*)(Kn16 + (size_t)rows[w][m] * EE);
            #pragma unroll 1
            for (int h = 0; h < HH; ++h) {
                float a = 0.f;
                #pragma unroll
                for (int k8 = 0; k8 < 4; ++k8) {
                    const uint4 u = kr[h * 4 + k8];
                    const float4 q0 = *(const float4*)&qh[w][h * 32 + k8 * 8];
                    const float4 q1 = *(const float4*)&qh[w][h * 32 + k8 * 8 + 4];
                    a += q0.x * bflo(u.x) + q0.y * bfhi(u.x)
                       + q0.z * bflo(u.y) + q0.w * bfhi(u.y)
                       + q1.x * bflo(u.z) + q1.y * bfhi(u.z)
                       + q1.z * bflo(u.w) + q1.w * bfhi(u.w);
                }
                s[h] = a * 0.17677669529663687f;
            }
        }
        #pragma unroll
        for (int h = 0; h < HH; ++h) {
            float mx = s[h];
            #pragma unroll
            for (int off = 16; off > 0; off >>= 1)
                mx = fmaxf(mx, __shfl_xor(mx, off, 32));
            const float ex = expf(s[h] - mx);
            float sum = ex;
            #pragma unroll
            for (int off = 16; off > 0; off >>= 1)
                sum += __shfl_xor(sum, off, 32);
            attn[w][h][m] = ex / sum;
        }
    }
    __syncthreads();

    {
        const int w = t >> 5, d0 = (t & 31) * 4;
        const int h = d0 >> 5;
        float4 a = {0.f, 0.f, 0.f, 0.f};
        #pragma unroll 4
        for (int m = 0; m < MM; ++m) {
            const float aw = attn[w][h][m];
            const u32* vr = (const u32*)(Vn16 + (size_t)rows[w][m] * EE + d0);
            const u32 u0 = vr[0], u1 = vr[1];
            a.x += aw * bflo(u0); a.y += aw * bfhi(u0);
            a.z += aw * bflo(u1); a.w += aw * bfhi(u1);
        }
        *(float4*)&osh[w][d0] = a;
    }
    __syncthreads();

    {
        const int g = t >> 7, i = t & 127;
        const float* wr = out_w + (size_t)i * EE;
        float acc[4] = {0.f, 0.f, 0.f, 0.f};
        #pragma unroll 4
        for (int k = 0; k < EE; k += 4) {
            const float4 wv = *(const float4*)&wr[k];
            #pragma unroll
            for (int w4 = 0; w4 < 4; ++w4) {
                const float* ow = osh[g * 4 + w4];
                acc[w4] += ow[k] * wv.x + ow[k + 1] * wv.y
                         + ow[k + 2] * wv.z + ow[k + 3] * wv.w;
            }
        }
        const float b = out_b[i];
        #pragma unroll
        for (int w4 = 0; w4 < 4; ++w4) {
            const int w = g * 4 + w4;
            we16[(size_t)(v0 + w) * EE + i] =
                (lenS[w] > 0) ? f2bf(acc[w4] + b) : (u16)0;
        }
    }
}

// ---------------------------------------------------------------------------
// Kernel B' (R17): per-word attention via precomputed Qn — the table gather
// (512 B/row fp32) and qh projection phase are replaced by a single bf16
// Qn-row gather (256 B/row): qh = (1/L) * sum_m Qn[rows[m]] (bias included).
// ---------------------------------------------------------------------------
__global__ __launch_bounds__(256, 3)
void word_attn_qn(const int* __restrict__ word2news,
                  const int* __restrict__ word2news_len,
                  const float* __restrict__ out_w,
                  const float* __restrict__ out_b,
                  const u16* __restrict__ Qn16,
                  const u16* __restrict__ Kn16,
                  const u16* __restrict__ Vn16,
                  u16* __restrict__ we16)
{
    const int v0 = blockIdx.x * WPB;
    const int t = threadIdx.x;

    __shared__ int   rows[WPB][MM];
    __shared__ int   lenS[WPB];
    __shared__ float qh[WPB][EE];
    __shared__ float attn[WPB][HH][MM];
    __shared__ float osh[WPB][EE];

    {
        const int w = t >> 5, m = t & 31;
        rows[w][m] = word2news[(size_t)(v0 + w) * MM + m];
        if (t < WPB) lenS[t] = word2news_len[v0 + t];
    }
    __syncthreads();

    // qh = mean of gathered Qn rows (bias included in Qn; exact because the
    // mean's weights sum to 1). Fixed trip, 4-deep pipelined loads.
    {
        const int w = t >> 5, d0 = (t & 31) * 4;
        const int L = lenS[w];
        float4 a = {0.f, 0.f, 0.f, 0.f};
        #pragma unroll 4
        for (int m = 0; m < MM; ++m) {
            const u32* qr = (const u32*)(Qn16 + (size_t)rows[w][m] * EE + d0);
            const u32 u0 = qr[0], u1 = qr[1];
            if (m < L) {
                a.x += bflo(u0); a.y += bfhi(u0);
                a.z += bflo(u1); a.w += bfhi(u1);
            }
        }
        const float inv = (L > 0) ? 1.0f / (float)L : 0.0f;
        a.x *= inv; a.y *= inv; a.z *= inv; a.w *= inv;
        *(float4*)&qh[w][d0] = a;
    }
    __syncthreads();

    // scores (gather Kn rows) + softmax over m; one head at a time.
    {
        const int w = t >> 5, m = t & 31;
        const int L = lenS[w];
        float s[HH] = {-1e9f, -1e9f, -1e9f, -1e9f};
        if (m < L) {
            const uint4* kr = (const uint4*)(Kn16 + (size_t)rows[w][m] * EE);
            #pragma unroll 1
            for (int h = 0; h < HH; ++h) {
                float a = 0.f;
                #pragma unroll
                for (int k8 = 0; k8 < 4; ++k8) {
                    const uint4 u = kr[h * 4 + k8];
                    const float4 q0 = *(const float4*)&qh[w][h * 32 + k8 * 8];
                    const float4 q1 = *(const float4*)&qh[w][h * 32 + k8 * 8 + 4];
                    a += q0.x * bflo(u.x) + q0.y * bfhi(u.x)
                       + q0.z * bflo(u.y) + q0.w * bfhi(u.y)
                       + q1.x * bflo(u.z) + q1.y * bfhi(u.z)
                       + q1.z * bflo(u.w) + q1.w * bfhi(u.w);
                }
                s[h] = a * 0.17677669529663687f;
            }
        }
        #pragma unroll
        for (int h = 0; h < HH; ++h) {
            float mx = s[h];
            #pragma unroll
            for (int off = 16; off > 0; off >>= 1)
                mx = fmaxf(mx, __shfl_xor(mx, off, 32));
            const float ex = expf(s[h] - mx);      // masked lanes underflow to 0
            float sum = ex;
            #pragma unroll
            for (int off = 16; off > 0; off >>= 1)
                sum += __shfl_xor(sum, off, 32);
            attn[w][h][m] = ex / sum;
        }
    }
    __syncthreads();

    // o = attn-weighted sum of Vn rows (fixed trip; attn==0 for m>=len)
    {
        const int w = t >> 5, d0 = (t & 31) * 4;
        const int h = d0 >> 5;
        float4 a = {0.f, 0.f, 0.f, 0.f};
        #pragma unroll 4
        for (int m = 0; m < MM; ++m) {
            const float aw = attn[w][h][m];
            const u32* vr = (const u32*)(Vn16 + (size_t)rows[w][m] * EE + d0);
            const u32 u0 = vr[0], u1 = vr[1];
            a.x += aw * bflo(u0); a.y += aw * bfhi(u0);
            a.z += aw * bflo(u1); a.w += aw * bfhi(u1);
        }
        *(float4*)&osh[w][d0] = a;
    }
    __syncthreads();

    // out proj + bf16 store (bounded 4-deep weight-load window)
    {
        const int g = t >> 7, i = t & 127;
        const float* wr = out_w + (size_t)i * EE;
        float acc[4] = {0.f, 0.f, 0.f, 0.f};
        #pragma unroll 4
        for (int k = 0; k < EE; k += 4) {
            const float4 wv = *(const float4*)&wr[k];
            #pragma unroll
            for (int w4 = 0; w4 < 4; ++w4) {
                const float* ow = osh[g * 4 + w4];
                acc[w4] += ow[k] * wv.x + ow[k + 1] * wv.y
                         + ow[k + 2] * wv.z + ow[k + 3] * wv.w;
            }
        }
        const float b = out_b[i];
        #pragma unroll
        for (int w4 = 0; w4 < 4; ++w4) {
            const int w = g * 4 + w4;
            we16[(size_t)(v0 + w) * EE + i] =
                (lenS[w] > 0) ? f2bf(acc[w4] + b) : (u16)0;
        }
    }
}

// ---------------------------------------------------------------------------
// Kernel 2 (R17): implicit-GEMM conv, 8 news per 1024-thread block.
// 16 waves; wave = (doc p = w>>1 of 8) x (channel-half nth = w&1).
// PER-WAVE SHAPE IDENTICAL TO THE MEASURED OPTIMUM (R12/R14/R16): acc 4x4
// f32x4 (64 AGPR), unroll-2 K-loop (64 arch + 64 AGPR, zero spill).
// (1024,4) -> cap 128/thread (same); single block/CU (all-or-nothing
// admission) = 16 waves/CU = 4 waves/SIMD. LDS 8 docs = 150.0 KB <= 160.
// GUARDRAIL: WRITE GB-scale => spill; occupancy < 20% => admission fail;
// either => revert to R16 (512-thread, 4-doc).
// ---------------------------------------------------------------------------
#define DSTRIDE 136              // u16 per doc row (16B-aligned, 68 words)
#define DOCSZ   (68 * DSTRIDE)   // u16 per doc (64 data rows + 4 zero rows)

template<int NSL, int SBASE, int NP>
__device__ __forceinline__ void conv_g2(const u16* __restrict__ lds,
                                        const u16* __restrict__ Bpack,
                                        const float* __restrict__ bk,
                                        int p, int nth, int l,
                                        float (&mxout)[4])
{
    f32x4 acc[4][4];
    #pragma unroll
    for (int mt = 0; mt < 4; ++mt)
        #pragma unroll
        for (int k = 0; k < 4; ++k)
            acc[mt][k] = (f32x4){0.f, 0.f, 0.f, 0.f};

    const int lm = l & 15;
    const int g  = l >> 4;
    const u16* bbase = Bpack + ((size_t)SBASE * 8 + nth * 4) * 512 + l * 8;
    const u16* abase = lds + (size_t)p * DOCSZ;

    #pragma unroll 2
    for (int s = 0; s < NSL; ++s) {
        const int j  = s >> 2;
        const int e0 = (s & 3) * 32;

        bf16x8 b[4];
        #pragma unroll
        for (int k = 0; k < 4; ++k)
            b[k] = *(const bf16x8*)(bbase + s * 4096 + k * 512);

        const u16* arow = abase + (lm + j) * DSTRIDE + e0 + g * 8;
        bf16x8 a[4];
        #pragma unroll
        for (int mt = 0; mt < 4; ++mt)
            a[mt] = *(const bf16x8*)(arow + mt * (16 * DSTRIDE));

        #pragma unroll
        for (int mt = 0; mt < 4; ++mt)
            #pragma unroll
            for (int k = 0; k < 4; ++k)
                acc[mt][k] = __builtin_amdgcn_mfma_f32_16x16x32_bf16(a[mt], b[k], acc[mt][k], 0, 0, 0);
    }

    // epilogue: +bias, relu, masked max over positions, reduce across row-groups
    #pragma unroll
    for (int k = 0; k < 4; ++k) {
        const int c = nth * 64 + k * 16 + lm;
        const float bias = bk[c];
        float mx = 0.0f;                     // relu output >= 0
        #pragma unroll
        for (int mt = 0; mt < 4; ++mt) {
            #pragma unroll
            for (int r = 0; r < 4; ++r) {
                const int pos = 16 * mt + g * 4 + r;
                const float y = fmaxf(acc[mt][k][r] + bias, 0.0f);
                if (pos < NP) mx = fmaxf(mx, y);
            }
        }
        mx = fmaxf(mx, __shfl_xor(mx, 16));
        mx = fmaxf(mx, __shfl_xor(mx, 32));
        mxout[k] = mx;
    }
}

__global__ __launch_bounds__(1024, 4)
void news_kernel(const int* __restrict__ news_words,
                 const u16* __restrict__ we16,
                 const u16* __restrict__ Bpack,
                 const float* __restrict__ b3,
                 const float* __restrict__ b4,
                 const float* __restrict__ b5,
                 const float* __restrict__ fcw, const float* __restrict__ fcb,
                 float* __restrict__ out)
{
    const int n0 = blockIdx.x * 8;
    const int t = threadIdx.x;
    const int w = t >> 6, l = t & 63;
    const int p = w >> 1, nth = w & 1;

    __shared__ u16 lds[8 * DOCSZ];           // 147,968 B; feats alias after convs
    __shared__ int rows[8 * LL];             // + 2,048 B = 150.0 KB

    if (t < 8 * LL) rows[t] = news_words[(size_t)n0 * LL + t];
    __syncthreads();

    // gather 8 docs as uint4 (16B) rows + zero the 4 pad rows per doc.
    // doc row = 16 data uint4 + 1 pad uint4 (stride 17); pads never read.
    {
        const uint4* weU = (const uint4*)we16;     // 16 uint4 per doc row
        uint4* ldsU = (uint4*)lds;                 // doc stride 1156 uint4
        for (int idx = t; idx < 8192; idx += 1024) {
            const int d = idx >> 10, rem = idx & 1023;
            const int row = rem >> 4, c4 = rem & 15;
            ldsU[d * 1156 + row * 17 + c4] = weU[(size_t)rows[d * 64 + row] * 16 + c4];
        }
        if (t < 512) {                             // 8 docs x 4 pad rows x 16
            const int d = t >> 6, rem = t & 63;
            const int row = 64 + (rem >> 4), c4 = rem & 15;
            ldsU[d * 1156 + row * 17 + c4] = (uint4){0u, 0u, 0u, 0u};
        }
    }
    __syncthreads();

    float m3[4], m4[4], m5[4];
    conv_g2<12,  0, 62>(lds, Bpack, b3, p, nth, l, m3);
    conv_g2<16, 12, 61>(lds, Bpack, b4, p, nth, l, m4);
    conv_g2<20, 28, 60>(lds, Bpack, b5, p, nth, l, m5);
    __syncthreads();                          // docs dead beyond this point

    float* feats = (float*)lds;               // [8][384] aliases doc buffer
    if ((l >> 4) == 0) {
        const int lm = l & 15;
        #pragma unroll
        for (int k = 0; k < 4; ++k) {
            const int c = nth * 64 + k * 16 + lm;
            feats[p * 384 +   0 + c] = m3[k];
            feats[p * 384 + 128 + c] = m4[k];
            feats[p * 384 + 256 + c] = m5[k];
        }
    }
    __syncthreads();

    // fc epilogue: threads 0..127, each output dim for all 8 docs
    if (t < 128) {
        const float4* wr4 = (const float4*)(fcw + (size_t)t * (3 * CC));
        float a[8];
        #pragma unroll
        for (int d = 0; d < 8; ++d) a[d] = fcb[t];
        for (int f4 = 0; f4 < 96; ++f4) {
            const float4 wv = wr4[f4];
            #pragma unroll
            for (int d = 0; d < 8; ++d) {
                const float4 x = *(const float4*)&feats[d * 384 + f4 * 4];
                a[d] += x.x * wv.x + x.y * wv.y + x.z * wv.z + x.w * wv.w;
            }
        }
        #pragma unroll
        for (int d = 0; d < 8; ++d)
            out[(size_t)(n0 + d) * EE + t] = a[d];
    }
}

// ---------------------------------------------------------------------------
extern "C" void kernel_launch(void* const* d_in, const int* in_sizes, int n_in,
                              void* d_out, int out_size, void* d_ws, size_t ws_size,
                              hipStream_t stream)
{
    const int*   word2news     = (const int*)d_in[0];
    const int*   word2news_len = (const int*)d_in[1];
    const int*   news_words    = (const int*)d_in[2];
    const float* table         = (const float*)d_in[3];
    const float* in_w          = (const float*)d_in[4];
    const float* in_b          = (const float*)d_in[5];
    const float* out_w         = (const float*)d_in[6];
    const float* out_b         = (const float*)d_in[7];
    const float* w3            = (const float*)d_in[8];
    const float* b3            = (const float*)d_in[9];
    const float* w4            = (const float*)d_in[10];
    const float* b4            = (const float*)d_in[11];
    const float* w5            = (const float*)d_in[12];
    const float* b5            = (const float*)d_in[13];
    const float* fcw           = (const float*)d_in[14];
    const float* fcb           = (const float*)d_in[15];

    float* out = (float*)d_out;
    u16* base  = (u16*)d_ws;
    u16* we16  = base;                                   // 2,560,000 u16 (5.12 MB)
    u16* Bpack = base + 2560000;                         //   196,608 u16
    u16* Kn16  = base + 2756608;                         // 1,048,576 u16
    u16* Vn16  = base + 3805184;                         // 1,048,576 u16  (9.71 MB)
    u16* Qn16  = base + 4853760;                         // 1,048,576 u16 (11.80 MB)
    const size_t need_qn = (size_t)(4853760 + 1048576) * 2;

    pack_weights<<<48, 256, 0, stream>>>(w3, w4, w5, Bpack);

    if (ws_size >= need_qn) {
        // Qn path: phase-fused word attention (ws_size is constant per
        // session, so the branch is graph-capture safe).
        kvq_proj_kernel<<<NN / 8, 384, 0, stream>>>(table, in_w, in_b,
                                                    Qn16, Kn16, Vn16);
        word_attn_qn<<<V_WORDS / WPB, 256, 0, stream>>>(
            word2news, word2news_len, out_w, out_b, Qn16, Kn16, Vn16, we16);
    } else {
        kv_proj_kernel<<<NN / 8, 256, 0, stream>>>(table, in_w, in_b, Kn16, Vn16);
        word_attn_kernel<<<V_WORDS / WPB, 256, 0, stream>>>(
            word2news, word2news_len, table, in_w, in_b, out_w, out_b,
            Kn16, Vn16, we16);
    }

    news_kernel<<<NN / 8, 1024, 0, stream>>>(
        news_words, we16, Bpack, b3, b4, b5, fcw, fcb, out);
}

// Round 18
// 422.202 us; speedup vs baseline: 1.2274x; 1.2274x over previous
//
#include <hip/hip_runtime.h>
#include <math.h>

#define V_WORDS 20000
#define MM 32
#define EE 128
#define HH 4
#define DHH 32
#define NN 8192
#define LL 64
#define CC 128

typedef short bf16x8 __attribute__((ext_vector_type(8)));
typedef float f32x4 __attribute__((ext_vector_type(4)));
typedef unsigned short u16;
typedef unsigned int u32;

__device__ __forceinline__ u16 f2bf(float x) {
    u32 u = __float_as_uint(x);
    u32 r = (u + 0x7FFFu + ((u >> 16) & 1u)) >> 16;
    return (u16)r;
}
__device__ __forceinline__ float bflo(u32 u) { return __uint_as_float(u << 16); }
__device__ __forceinline__ float bfhi(u32 u) { return __uint_as_float(u & 0xFFFF0000u); }

// ---------------------------------------------------------------------------
// Kernel 0: pack conv weights into bf16 MFMA B-fragment order (unchanged).
// ---------------------------------------------------------------------------
__global__ __launch_bounds__(256)
void pack_weights(const float* __restrict__ w3,
                  const float* __restrict__ w4,
                  const float* __restrict__ w5,
                  u16* __restrict__ Bpack)
{
    const int s = blockIdx.x;
    const int t = threadIdx.x;
    const int lane = t & 63;

    const float* src;
    int K, sl;
    if (s < 12)      { src = w3; K = 3; sl = s; }
    else if (s < 28) { src = w4; K = 4; sl = s - 12; }
    else             { src = w5; K = 5; sl = s - 28; }
    const int j  = sl >> 2;
    const int e0 = (sl & 3) * 32;

    for (int nt = (t >> 6); nt < 8; nt += 4) {
        const int c = nt * 16 + (lane & 15);
        const int kb = (lane >> 4) * 8;
        u16 vals[8];
        #pragma unroll
        for (int i = 0; i < 8; ++i) {
            const int e = e0 + kb + i;
            vals[i] = f2bf(src[(c * EE + e) * K + j]);
        }
        u16* dst = Bpack + (((size_t)s * 8 + nt) * 64 + lane) * 8;
        *(bf16x8*)dst = *(const bf16x8*)vals;
    }
}

// ---------------------------------------------------------------------------
// Kernel A (fallback): Kn/Vn projections (R15 path).
// ---------------------------------------------------------------------------
__global__ __launch_bounds__(256)
void kv_proj_kernel(const float* __restrict__ table,
                    const float* __restrict__ in_w,
                    const float* __restrict__ in_b,
                    u16* __restrict__ Kn16, u16* __restrict__ Vn16)
{
    const int n0 = blockIdx.x * 8;
    const int t = threadIdx.x;
    __shared__ float tbl[8][EE];
    {
        const int r = t >> 5, q4 = (t & 31) * 4;
        *(float4*)&tbl[r][q4] = *(const float4*)&table[(size_t)(n0 + r) * EE + q4];
    }
    __syncthreads();

    const int sel = t >> 7;
    const int i = t & 127;
    const float* w = in_w + (size_t)(sel + 1) * EE * EE + (size_t)i * EE;
    const float bias = in_b[(sel + 1) * EE + i];

    float acc[8];
    #pragma unroll
    for (int r = 0; r < 8; ++r) acc[r] = bias;
    for (int k = 0; k < EE; k += 4) {
        const float4 wv = *(const float4*)&w[k];
        #pragma unroll
        for (int r = 0; r < 8; ++r) {
            acc[r] += tbl[r][k]     * wv.x + tbl[r][k + 1] * wv.y
                    + tbl[r][k + 2] * wv.z + tbl[r][k + 3] * wv.w;
        }
    }
    u16* dst = sel ? Vn16 : Kn16;
    #pragma unroll
    for (int r = 0; r < 8; ++r) dst[(size_t)(n0 + r) * EE + i] = f2bf(acc[r]);
}

// ---------------------------------------------------------------------------
// Kernel A': Q/K/V projections over the 8192 distinct news rows (R17 winner).
// 384 threads = {Q,K,V} x 128 dims, 8 rows/block. Qn includes bias: since
// the masked mean's weights sum to 1, mean_m(Qn[rows[m]]) == q @ wq^T + bq.
// ---------------------------------------------------------------------------
__global__ __launch_bounds__(384)
void kvq_proj_kernel(const float* __restrict__ table,
                     const float* __restrict__ in_w,
                     const float* __restrict__ in_b,
                     u16* __restrict__ Qn16,
                     u16* __restrict__ Kn16,
                     u16* __restrict__ Vn16)
{
    const int n0 = blockIdx.x * 8;
    const int t = threadIdx.x;
    __shared__ float tbl[8][EE];
    if (t < 256) {
        const int r = t >> 5, q4 = (t & 31) * 4;
        *(float4*)&tbl[r][q4] = *(const float4*)&table[(size_t)(n0 + r) * EE + q4];
    }
    __syncthreads();

    const int sel = t >> 7;                 // 0 = Q, 1 = K, 2 = V
    const int i = t & 127;
    const float* w = in_w + (size_t)sel * EE * EE + (size_t)i * EE;
    const float bias = in_b[sel * EE + i];

    float acc[8];
    #pragma unroll
    for (int r = 0; r < 8; ++r) acc[r] = bias;
    for (int k = 0; k < EE; k += 4) {
        const float4 wv = *(const float4*)&w[k];
        #pragma unroll
        for (int r = 0; r < 8; ++r) {
            acc[r] += tbl[r][k]     * wv.x + tbl[r][k + 1] * wv.y
                    + tbl[r][k + 2] * wv.z + tbl[r][k + 3] * wv.w;
        }
    }
    u16* dst = (sel == 0) ? Qn16 : (sel == 1) ? Kn16 : Vn16;
    #pragma unroll
    for (int r = 0; r < 8; ++r) dst[(size_t)(n0 + r) * EE + i] = f2bf(acc[r]);
}

// ---------------------------------------------------------------------------
// Kernel B (fallback): per-word attention, R15 path.
// ---------------------------------------------------------------------------
#define WPB 8
__global__ __launch_bounds__(256, 3)
void word_attn_kernel(const int* __restrict__ word2news,
                      const int* __restrict__ word2news_len,
                      const float* __restrict__ table,
                      const float* __restrict__ in_w,
                      const float* __restrict__ in_b,
                      const float* __restrict__ out_w,
                      const float* __restrict__ out_b,
                      const u16* __restrict__ Kn16,
                      const u16* __restrict__ Vn16,
                      u16* __restrict__ we16)
{
    const int v0 = blockIdx.x * WPB;
    const int t = threadIdx.x;

    __shared__ int   rows[WPB][MM];
    __shared__ int   lenS[WPB];
    __shared__ float q[WPB][EE];
    __shared__ float qh[WPB][EE];
    __shared__ float attn[WPB][HH][MM];
    __shared__ float osh[WPB][EE];

    {
        const int w = t >> 5, m = t & 31;
        rows[w][m] = word2news[(size_t)(v0 + w) * MM + m];
        if (t < WPB) lenS[t] = word2news_len[v0 + t];
    }
    __syncthreads();

    {
        const int w = t >> 5, d0 = (t & 31) * 4;
        const int L = lenS[w];
        float4 a = {0.f, 0.f, 0.f, 0.f};
        #pragma unroll 4
        for (int m = 0; m < MM; ++m) {
            const float4 x = *(const float4*)&table[(size_t)rows[w][m] * EE + d0];
            if (m < L) { a.x += x.x; a.y += x.y; a.z += x.z; a.w += x.w; }
        }
        const float inv = (L > 0) ? 1.0f / (float)L : 0.0f;
        a.x *= inv; a.y *= inv; a.z *= inv; a.w *= inv;
        *(float4*)&q[w][d0] = a;
    }
    __syncthreads();

    {
        const int g = t >> 7, i = t & 127;
        const float* wr = in_w + (size_t)i * EE;
        float acc[4] = {0.f, 0.f, 0.f, 0.f};
        #pragma unroll 4
        for (int k = 0; k < EE; k += 4) {
            const float4 wv = *(const float4*)&wr[k];
            #pragma unroll
            for (int w4 = 0; w4 < 4; ++w4) {
                const float* qw = q[g * 4 + w4];
                acc[w4] += qw[k] * wv.x + qw[k + 1] * wv.y
                         + qw[k + 2] * wv.z + qw[k + 3] * wv.w;
            }
        }
        const float b = in_b[i];
        #pragma unroll
        for (int w4 = 0; w4 < 4; ++w4) qh[g * 4 + w4][i] = acc[w4] + b;
    }
    __syncthreads();

    {
        const int w = t >> 5, m = t & 31;
        const int L = lenS[w];
        float s[HH] = {-1e9f, -1e9f, -1e9f, -1e9f};
        if (m < L) {
            const uint4* kr = (const uint4*)(Kn16 + (size_t)rows[w][m] * EE);
            #pragma unroll 1
            for (int h = 0; h < HH; ++h) {
                float a = 0.f;
                #pragma unroll
                for (int k8 = 0; k8 < 4; ++k8) {
                    const uint4 u = kr[h * 4 + k8];
                    const float4 q0 = *(const float4*)&qh[w][h * 32 + k8 * 8];
                    const float4 q1 = *(const float4*)&qh[w][h * 32 + k8 * 8 + 4];
                    a += q0.x * bflo(u.x) + q0.y * bfhi(u.x)
                       + q0.z * bflo(u.y) + q0.w * bfhi(u.y)
                       + q1.x * bflo(u.z) + q1.y * bfhi(u.z)
                       + q1.z * bflo(u.w) + q1.w * bfhi(u.w);
                }
                s[h] = a * 0.17677669529663687f;
            }
        }
        #pragma unroll
        for (int h = 0; h < HH; ++h) {
            float mx = s[h];
            #pragma unroll
            for (int off = 16; off > 0; off >>= 1)
                mx = fmaxf(mx, __shfl_xor(mx, off, 32));
            const float ex = expf(s[h] - mx);
            float sum = ex;
            #pragma unroll
            for (int off = 16; off > 0; off >>= 1)
                sum += __shfl_xor(sum, off, 32);
            attn[w][h][m] = ex / sum;
        }
    }
    __syncthreads();

    {
        const int w = t >> 5, d0 = (t & 31) * 4;
        const int h = d0 >> 5;
        float4 a = {0.f, 0.f, 0.f, 0.f};
        #pragma unroll 4
        for (int m = 0; m < MM; ++m) {
            const float aw = attn[w][h][m];
            const u32* vr = (const u32*)(Vn16 + (size_t)rows[w][m] * EE + d0);
            const u32 u0 = vr[0], u1 = vr[1];
            a.x += aw * bflo(u0); a.y += aw * bfhi(u0);
            a.z += aw * bflo(u1); a.w += aw * bfhi(u1);
        }
        *(float4*)&osh[w][d0] = a;
    }
    __syncthreads();

    {
        const int g = t >> 7, i = t & 127;
        const float* wr = out_w + (size_t)i * EE;
        float acc[4] = {0.f, 0.f, 0.f, 0.f};
        #pragma unroll 4
        for (int k = 0; k < EE; k += 4) {
            const float4 wv = *(const float4*)&wr[k];
            #pragma unroll
            for (int w4 = 0; w4 < 4; ++w4) {
                const float* ow = osh[g * 4 + w4];
                acc[w4] += ow[k] * wv.x + ow[k + 1] * wv.y
                         + ow[k + 2] * wv.z + ow[k + 3] * wv.w;
            }
        }
        const float b = out_b[i];
        #pragma unroll
        for (int w4 = 0; w4 < 4; ++w4) {
            const int w = g * 4 + w4;
            we16[(size_t)(v0 + w) * EE + i] =
                (lenS[w] > 0) ? f2bf(acc[w4] + b) : (u16)0;
        }
    }
}

// ---------------------------------------------------------------------------
// Kernel B': per-word attention via precomputed Qn (R17 winner — saved
// ~32 us vs the fallback): the fp32 table gather and qh projection phase
// are replaced by a single bf16 Qn-row gather, qh = (1/L) sum_m Qn[rows[m]].
// ---------------------------------------------------------------------------
__global__ __launch_bounds__(256, 3)
void word_attn_qn(const int* __restrict__ word2news,
                  const int* __restrict__ word2news_len,
                  const float* __restrict__ out_w,
                  const float* __restrict__ out_b,
                  const u16* __restrict__ Qn16,
                  const u16* __restrict__ Kn16,
                  const u16* __restrict__ Vn16,
                  u16* __restrict__ we16)
{
    const int v0 = blockIdx.x * WPB;
    const int t = threadIdx.x;

    __shared__ int   rows[WPB][MM];
    __shared__ int   lenS[WPB];
    __shared__ float qh[WPB][EE];
    __shared__ float attn[WPB][HH][MM];
    __shared__ float osh[WPB][EE];

    {
        const int w = t >> 5, m = t & 31;
        rows[w][m] = word2news[(size_t)(v0 + w) * MM + m];
        if (t < WPB) lenS[t] = word2news_len[v0 + t];
    }
    __syncthreads();

    // qh = mean of gathered Qn rows (bias included; exact — weights sum to 1)
    {
        const int w = t >> 5, d0 = (t & 31) * 4;
        const int L = lenS[w];
        float4 a = {0.f, 0.f, 0.f, 0.f};
        #pragma unroll 4
        for (int m = 0; m < MM; ++m) {
            const u32* qr = (const u32*)(Qn16 + (size_t)rows[w][m] * EE + d0);
            const u32 u0 = qr[0], u1 = qr[1];
            if (m < L) {
                a.x += bflo(u0); a.y += bfhi(u0);
                a.z += bflo(u1); a.w += bfhi(u1);
            }
        }
        const float inv = (L > 0) ? 1.0f / (float)L : 0.0f;
        a.x *= inv; a.y *= inv; a.z *= inv; a.w *= inv;
        *(float4*)&qh[w][d0] = a;
    }
    __syncthreads();

    // scores (gather Kn rows) + softmax over m; one head at a time.
    {
        const int w = t >> 5, m = t & 31;
        const int L = lenS[w];
        float s[HH] = {-1e9f, -1e9f, -1e9f, -1e9f};
        if (m < L) {
            const uint4* kr = (const uint4*)(Kn16 + (size_t)rows[w][m] * EE);
            #pragma unroll 1
            for (int h = 0; h < HH; ++h) {
                float a = 0.f;
                #pragma unroll
                for (int k8 = 0; k8 < 4; ++k8) {
                    const uint4 u = kr[h * 4 + k8];
                    const float4 q0 = *(const float4*)&qh[w][h * 32 + k8 * 8];
                    const float4 q1 = *(const float4*)&qh[w][h * 32 + k8 * 8 + 4];
                    a += q0.x * bflo(u.x) + q0.y * bfhi(u.x)
                       + q0.z * bflo(u.y) + q0.w * bfhi(u.y)
                       + q1.x * bflo(u.z) + q1.y * bfhi(u.z)
                       + q1.z * bflo(u.w) + q1.w * bfhi(u.w);
                }
                s[h] = a * 0.17677669529663687f;
            }
        }
        #pragma unroll
        for (int h = 0; h < HH; ++h) {
            float mx = s[h];
            #pragma unroll
            for (int off = 16; off > 0; off >>= 1)
                mx = fmaxf(mx, __shfl_xor(mx, off, 32));
            const float ex = expf(s[h] - mx);      // masked lanes underflow to 0
            float sum = ex;
            #pragma unroll
            for (int off = 16; off > 0; off >>= 1)
                sum += __shfl_xor(sum, off, 32);
            attn[w][h][m] = ex / sum;
        }
    }
    __syncthreads();

    // o = attn-weighted sum of Vn rows (fixed trip; attn==0 for m>=len)
    {
        const int w = t >> 5, d0 = (t & 31) * 4;
        const int h = d0 >> 5;
        float4 a = {0.f, 0.f, 0.f, 0.f};
        #pragma unroll 4
        for (int m = 0; m < MM; ++m) {
            const float aw = attn[w][h][m];
            const u32* vr = (const u32*)(Vn16 + (size_t)rows[w][m] * EE + d0);
            const u32 u0 = vr[0], u1 = vr[1];
            a.x += aw * bflo(u0); a.y += aw * bfhi(u0);
            a.z += aw * bflo(u1); a.w += aw * bfhi(u1);
        }
        *(float4*)&osh[w][d0] = a;
    }
    __syncthreads();

    // out proj + bf16 store (bounded 4-deep weight-load window)
    {
        const int g = t >> 7, i = t & 127;
        const float* wr = out_w + (size_t)i * EE;
        float acc[4] = {0.f, 0.f, 0.f, 0.f};
        #pragma unroll 4
        for (int k = 0; k < EE; k += 4) {
            const float4 wv = *(const float4*)&wr[k];
            #pragma unroll
            for (int w4 = 0; w4 < 4; ++w4) {
                const float* ow = osh[g * 4 + w4];
                acc[w4] += ow[k] * wv.x + ow[k + 1] * wv.y
                         + ow[k + 2] * wv.z + ow[k + 3] * wv.w;
            }
        }
        const float b = out_b[i];
        #pragma unroll
        for (int w4 = 0; w4 < 4; ++w4) {
            const int w = g * 4 + w4;
            we16[(size_t)(v0 + w) * EE + i] =
                (lenS[w] > 0) ? f2bf(acc[w4] + b) : (u16)0;
        }
    }
}

// ---------------------------------------------------------------------------
// Kernel 2: implicit-GEMM conv — R16 MEASURED OPTIMUM, restored verbatim.
// 512 threads / 4 docs per block; 8 waves; wave = (doc p) x (channel-half).
// Per-wave: acc 4x4 f32x4 (64 AGPR), unroll-2 K-loop -> 64 arch + 64 AGPR,
// zero spill; (512,4) cap 128 == measured demand; 2 blocks/CU = 16 waves/CU.
// ENVELOPE MAP (measured): 256thr/2doc=242us, 512thr/4doc=209us,
// 1024thr/8doc=329us (single barrier domain convoys all 16 waves, no
// cross-block overlap). DO NOT grow the block past 512.
// ---------------------------------------------------------------------------
#define DSTRIDE 136              // u16 per doc row (16B-aligned, 68 words)
#define DOCSZ   (68 * DSTRIDE)   // u16 per doc (64 data rows + 4 zero rows)

template<int NSL, int SBASE, int NP>
__device__ __forceinline__ void conv_g2(const u16* __restrict__ lds,
                                        const u16* __restrict__ Bpack,
                                        const float* __restrict__ bk,
                                        int p, int nth, int l,
                                        float (&mxout)[4])
{
    f32x4 acc[4][4];
    #pragma unroll
    for (int mt = 0; mt < 4; ++mt)
        #pragma unroll
        for (int k = 0; k < 4; ++k)
            acc[mt][k] = (f32x4){0.f, 0.f, 0.f, 0.f};

    const int lm = l & 15;
    const int g  = l >> 4;
    const u16* bbase = Bpack + ((size_t)SBASE * 8 + nth * 4) * 512 + l * 8;
    const u16* abase = lds + (size_t)p * DOCSZ;

    #pragma unroll 2
    for (int s = 0; s < NSL; ++s) {
        const int j  = s >> 2;
        const int e0 = (s & 3) * 32;

        bf16x8 b[4];
        #pragma unroll
        for (int k = 0; k < 4; ++k)
            b[k] = *(const bf16x8*)(bbase + s * 4096 + k * 512);

        const u16* arow = abase + (lm + j) * DSTRIDE + e0 + g * 8;
        bf16x8 a[4];
        #pragma unroll
        for (int mt = 0; mt < 4; ++mt)
            a[mt] = *(const bf16x8*)(arow + mt * (16 * DSTRIDE));

        #pragma unroll
        for (int mt = 0; mt < 4; ++mt)
            #pragma unroll
            for (int k = 0; k < 4; ++k)
                acc[mt][k] = __builtin_amdgcn_mfma_f32_16x16x32_bf16(a[mt], b[k], acc[mt][k], 0, 0, 0);
    }

    // epilogue: +bias, relu, masked max over positions, reduce across row-groups
    #pragma unroll
    for (int k = 0; k < 4; ++k) {
        const int c = nth * 64 + k * 16 + lm;
        const float bias = bk[c];
        float mx = 0.0f;                     // relu output >= 0
        #pragma unroll
        for (int mt = 0; mt < 4; ++mt) {
            #pragma unroll
            for (int r = 0; r < 4; ++r) {
                const int pos = 16 * mt + g * 4 + r;
                const float y = fmaxf(acc[mt][k][r] + bias, 0.0f);
                if (pos < NP) mx = fmaxf(mx, y);
            }
        }
        mx = fmaxf(mx, __shfl_xor(mx, 16));
        mx = fmaxf(mx, __shfl_xor(mx, 32));
        mxout[k] = mx;
    }
}

__global__ __launch_bounds__(512, 4)
void news_kernel(const int* __restrict__ news_words,
                 const u16* __restrict__ we16,
                 const u16* __restrict__ Bpack,
                 const float* __restrict__ b3,
                 const float* __restrict__ b4,
                 const float* __restrict__ b5,
                 const float* __restrict__ fcw, const float* __restrict__ fcb,
                 float* __restrict__ out)
{
    const int n0 = blockIdx.x * 4;
    const int t = threadIdx.x;
    const int w = t >> 6, l = t & 63;
    const int p = w >> 1, nth = w & 1;

    __shared__ u16 lds[4 * DOCSZ];           // 73,984 B; feats alias after convs
    __shared__ int rows[4 * LL];

    if (t < 4 * LL) rows[t] = news_words[(size_t)n0 * LL + t];
    __syncthreads();

    // gather 4 docs as uint4 (16B) rows + zero the 4 pad rows per doc.
    // doc row = 16 data uint4 + 1 pad uint4 (stride 17); pads never read.
    {
        const uint4* weU = (const uint4*)we16;     // 16 uint4 per doc row
        uint4* ldsU = (uint4*)lds;                 // doc stride 1156 uint4
        for (int idx = t; idx < 4096; idx += 512) {
            const int d = idx >> 10, rem = idx & 1023;
            const int row = rem >> 4, c4 = rem & 15;
            ldsU[d * 1156 + row * 17 + c4] = weU[(size_t)rows[d * 64 + row] * 16 + c4];
        }
        if (t < 256) {                             // 4 docs x 4 pad rows x 16
            const int d = t >> 6, rem = t & 63;
            const int row = 64 + (rem >> 4), c4 = rem & 15;
            ldsU[d * 1156 + row * 17 + c4] = (uint4){0u, 0u, 0u, 0u};
        }
    }
    __syncthreads();

    float m3[4], m4[4], m5[4];
    conv_g2<12,  0, 62>(lds, Bpack, b3, p, nth, l, m3);
    conv_g2<16, 12, 61>(lds, Bpack, b4, p, nth, l, m4);
    conv_g2<20, 28, 60>(lds, Bpack, b5, p, nth, l, m5);
    __syncthreads();                          // docs dead beyond this point

    float* feats = (float*)lds;               // [4][384] aliases doc buffer
    if ((l >> 4) == 0) {
        const int lm = l & 15;
        #pragma unroll
        for (int k = 0; k < 4; ++k) {
            const int c = nth * 64 + k * 16 + lm;
            feats[p * 384 +   0 + c] = m3[k];
            feats[p * 384 + 128 + c] = m4[k];
            feats[p * 384 + 256 + c] = m5[k];
        }
    }
    __syncthreads();

    // fc epilogue: threads 0..127, each output dim for all 4 docs
    if (t < 128) {
        const float4* wr4 = (const float4*)(fcw + (size_t)t * (3 * CC));
        float a0 = fcb[t], a1 = a0, a2 = a0, a3 = a0;
        for (int f4 = 0; f4 < 96; ++f4) {
            const float4 wv = wr4[f4];
            const float4 x0 = *(const float4*)&feats[0 * 384 + f4 * 4];
            const float4 x1 = *(const float4*)&feats[1 * 384 + f4 * 4];
            const float4 x2 = *(const float4*)&feats[2 * 384 + f4 * 4];
            const float4 x3 = *(const float4*)&feats[3 * 384 + f4 * 4];
            a0 += x0.x * wv.x + x0.y * wv.y + x0.z * wv.z + x0.w * wv.w;
            a1 += x1.x * wv.x + x1.y * wv.y + x1.z * wv.z + x1.w * wv.w;
            a2 += x2.x * wv.x + x2.y * wv.y + x2.z * wv.z + x2.w * wv.w;
            a3 += x3.x * wv.x + x3.y * wv.y + x3.z * wv.z + x3.w * wv.w;
        }
        out[(size_t)(n0 + 0) * EE + t] = a0;
        out[(size_t)(n0 + 1) * EE + t] = a1;
        out[(size_t)(n0 + 2) * EE + t] = a2;
        out[(size_t)(n0 + 3) * EE + t] = a3;
    }
}

// ---------------------------------------------------------------------------
extern "C" void kernel_launch(void* const* d_in, const int* in_sizes, int n_in,
                              void* d_out, int out_size, void* d_ws, size_t ws_size,
                              hipStream_t stream)
{
    const int*   word2news     = (const int*)d_in[0];
    const int*   word2news_len = (const int*)d_in[1];
    const int*   news_words    = (const int*)d_in[2];
    const float* table         = (const float*)d_in[3];
    const float* in_w          = (const float*)d_in[4];
    const float* in_b          = (const float*)d_in[5];
    const float* out_w         = (const float*)d_in[6];
    const float* out_b         = (const float*)d_in[7];
    const float* w3            = (const float*)d_in[8];
    const float* b3            = (const float*)d_in[9];
    const float* w4            = (const float*)d_in[10];
    const float* b4            = (const float*)d_in[11];
    const float* w5            = (const float*)d_in[12];
    const float* b5            = (const float*)d_in[13];
    const float* fcw           = (const float*)d_in[14];
    const float* fcb           = (const float*)d_in[15];

    float* out = (float*)d_out;
    u16* base  = (u16*)d_ws;
    u16* we16  = base;                                   // 2,560,000 u16 (5.12 MB)
    u16* Bpack = base + 2560000;                         //   196,608 u16
    u16* Kn16  = base + 2756608;                         // 1,048,576 u16
    u16* Vn16  = base + 3805184;                         // 1,048,576 u16  (9.71 MB)
    u16* Qn16  = base + 4853760;                         // 1,048,576 u16 (11.80 MB)
    const size_t need_qn = (size_t)(4853760 + 1048576) * 2;

    pack_weights<<<48, 256, 0, stream>>>(w3, w4, w5, Bpack);

    if (ws_size >= need_qn) {
        // Qn path: phase-fused word attention (ws_size constant per session
        // -> branch is graph-capture safe).
        kvq_proj_kernel<<<NN / 8, 384, 0, stream>>>(table, in_w, in_b,
                                                    Qn16, Kn16, Vn16);
        word_attn_qn<<<V_WORDS / WPB, 256, 0, stream>>>(
            word2news, word2news_len, out_w, out_b, Qn16, Kn16, Vn16, we16);
    } else {
        kv_proj_kernel<<<NN / 8, 256, 0, stream>>>(table, in_w, in_b, Kn16, Vn16);
        word_attn_kernel<<<V_WORDS / WPB, 256, 0, stream>>>(
            word2news, word2news_len, table, in_w, in_b, out_w, out_b,
            Kn16, Vn16, we16);
    }

    news_kernel<<<NN / 4, 512, 0, stream>>>(
        news_words, we16, Bpack, b3, b4, b5, fcw, fcb, out);
}

// Round 19
// 401.765 us; speedup vs baseline: 1.2898x; 1.0509x over previous
//
#include <hip/hip_runtime.h>
#include <math.h>

#define V_WORDS 20000
#define MM 32
#define EE 128
#define HH 4
#define DHH 32
#define NN 8192
#define LL 64
#define CC 128

typedef short bf16x8 __attribute__((ext_vector_type(8)));
typedef float f32x4 __attribute__((ext_vector_type(4)));
typedef unsigned short u16;
typedef unsigned int u32;

__device__ __forceinline__ u16 f2bf(float x) {
    u32 u = __float_as_uint(x);
    u32 r = (u + 0x7FFFu + ((u >> 16) & 1u)) >> 16;
    return (u16)r;
}
__device__ __forceinline__ float bflo(u32 u) { return __uint_as_float(u << 16); }
__device__ __forceinline__ float bfhi(u32 u) { return __uint_as_float(u & 0xFFFF0000u); }

// ---------------------------------------------------------------------------
// Kernel 0: pack conv weights into bf16 MFMA B-fragment order (unchanged).
// ---------------------------------------------------------------------------
__global__ __launch_bounds__(256)
void pack_weights(const float* __restrict__ w3,
                  const float* __restrict__ w4,
                  const float* __restrict__ w5,
                  u16* __restrict__ Bpack)
{
    const int s = blockIdx.x;
    const int t = threadIdx.x;
    const int lane = t & 63;

    const float* src;
    int K, sl;
    if (s < 12)      { src = w3; K = 3; sl = s; }
    else if (s < 28) { src = w4; K = 4; sl = s - 12; }
    else             { src = w5; K = 5; sl = s - 28; }
    const int j  = sl >> 2;
    const int e0 = (sl & 3) * 32;

    for (int nt = (t >> 6); nt < 8; nt += 4) {
        const int c = nt * 16 + (lane & 15);
        const int kb = (lane >> 4) * 8;
        u16 vals[8];
        #pragma unroll
        for (int i = 0; i < 8; ++i) {
            const int e = e0 + kb + i;
            vals[i] = f2bf(src[(c * EE + e) * K + j]);
        }
        u16* dst = Bpack + (((size_t)s * 8 + nt) * 64 + lane) * 8;
        *(bf16x8*)dst = *(const bf16x8*)vals;
    }
}

// ---------------------------------------------------------------------------
// Kernel A (fallback, ws too small): Kn/Vn projections (R15 path).
// ---------------------------------------------------------------------------
__global__ __launch_bounds__(256)
void kv_proj_kernel(const float* __restrict__ table,
                    const float* __restrict__ in_w,
                    const float* __restrict__ in_b,
                    u16* __restrict__ Kn16, u16* __restrict__ Vn16)
{
    const int n0 = blockIdx.x * 8;
    const int t = threadIdx.x;
    __shared__ float tbl[8][EE];
    {
        const int r = t >> 5, q4 = (t & 31) * 4;
        *(float4*)&tbl[r][q4] = *(const float4*)&table[(size_t)(n0 + r) * EE + q4];
    }
    __syncthreads();

    const int sel = t >> 7;
    const int i = t & 127;
    const float* w = in_w + (size_t)(sel + 1) * EE * EE + (size_t)i * EE;
    const float bias = in_b[(sel + 1) * EE + i];

    float acc[8];
    #pragma unroll
    for (int r = 0; r < 8; ++r) acc[r] = bias;
    for (int k = 0; k < EE; k += 4) {
        const float4 wv = *(const float4*)&w[k];
        #pragma unroll
        for (int r = 0; r < 8; ++r) {
            acc[r] += tbl[r][k]     * wv.x + tbl[r][k + 1] * wv.y
                    + tbl[r][k + 2] * wv.z + tbl[r][k + 3] * wv.w;
        }
    }
    u16* dst = sel ? Vn16 : Kn16;
    #pragma unroll
    for (int r = 0; r < 8; ++r) dst[(size_t)(n0 + r) * EE + i] = f2bf(acc[r]);
}

// ---------------------------------------------------------------------------
// Kernel A'' (R19): Q/K/W projections over the 8192 distinct news rows.
// 384 threads = {Q,K,V} x 128 dims, 8 rows/block, then a second phase folds
// the out-projection into V:  Wn = (table@wv^T + bv) @ out_w^T + out_b.
// ALGEBRA: softmax output is a convex combination (sum attn = 1), and the
// out-projection is linear, so we = sum_m attn_m * Wn[rows[m]] exactly.
// This deletes word_attn's out-proj phase + its 320 MB of out_w L2 traffic.
// ---------------------------------------------------------------------------
__global__ __launch_bounds__(384)
void kvqw_proj_kernel(const float* __restrict__ table,
                      const float* __restrict__ in_w,
                      const float* __restrict__ in_b,
                      const float* __restrict__ out_w,
                      const float* __restrict__ out_b,
                      u16* __restrict__ Qn16,
                      u16* __restrict__ Kn16,
                      u16* __restrict__ Wn16)
{
    const int n0 = blockIdx.x * 8;
    const int t = threadIdx.x;
    __shared__ float tbl[8][EE];
    __shared__ float vsh[8][EE];
    if (t < 256) {
        const int r = t >> 5, q4 = (t & 31) * 4;
        *(float4*)&tbl[r][q4] = *(const float4*)&table[(size_t)(n0 + r) * EE + q4];
    }
    __syncthreads();

    const int sel = t >> 7;                 // 0 = Q, 1 = K, 2 = V
    const int i = t & 127;
    const float* w = in_w + (size_t)sel * EE * EE + (size_t)i * EE;
    const float bias = in_b[sel * EE + i];

    float acc[8];
    #pragma unroll
    for (int r = 0; r < 8; ++r) acc[r] = bias;
    for (int k = 0; k < EE; k += 4) {
        const float4 wv = *(const float4*)&w[k];
        #pragma unroll
        for (int r = 0; r < 8; ++r) {
            acc[r] += tbl[r][k]     * wv.x + tbl[r][k + 1] * wv.y
                    + tbl[r][k + 2] * wv.z + tbl[r][k + 3] * wv.w;
        }
    }
    if (sel == 0) {
        #pragma unroll
        for (int r = 0; r < 8; ++r) Qn16[(size_t)(n0 + r) * EE + i] = f2bf(acc[r]);
    } else if (sel == 1) {
        #pragma unroll
        for (int r = 0; r < 8; ++r) Kn16[(size_t)(n0 + r) * EE + i] = f2bf(acc[r]);
    } else {
        #pragma unroll
        for (int r = 0; r < 8; ++r) vsh[r][i] = acc[r];   // keep V fp32 for phase 2
    }
    __syncthreads();

    // Phase 2: Wn[r][i] = vsh[r] . out_w[i] + out_b[i]; 3 thread-groups of
    // 128 cover rows {g, g+3, g+6} with one shared pass over the weight row.
    {
        const int g = t >> 7;
        const int r0 = g, r1 = g + 3, r2 = g + 6;       // r2 == 8 invalid for g==2
        const int r2c = (r2 < 8) ? r2 : 7;
        const float* wr = out_w + (size_t)i * EE;
        const float ob = out_b[i];
        float a0 = ob, a1 = ob, a2 = ob;
        #pragma unroll 4
        for (int k = 0; k < EE; k += 4) {
            const float4 wv = *(const float4*)&wr[k];
            a0 += vsh[r0][k]   * wv.x + vsh[r0][k+1] * wv.y
                + vsh[r0][k+2] * wv.z + vsh[r0][k+3] * wv.w;
            a1 += vsh[r1][k]   * wv.x + vsh[r1][k+1] * wv.y
                + vsh[r1][k+2] * wv.z + vsh[r1][k+3] * wv.w;
            a2 += vsh[r2c][k]   * wv.x + vsh[r2c][k+1] * wv.y
                + vsh[r2c][k+2] * wv.z + vsh[r2c][k+3] * wv.w;
        }
        Wn16[(size_t)(n0 + r0) * EE + i] = f2bf(a0);
        Wn16[(size_t)(n0 + r1) * EE + i] = f2bf(a1);
        if (r2 < 8) Wn16[(size_t)(n0 + r2) * EE + i] = f2bf(a2);
    }
}

// ---------------------------------------------------------------------------
// Kernel B (fallback): per-word attention, R15 path (unchanged).
// ---------------------------------------------------------------------------
#define WPB 8
__global__ __launch_bounds__(256, 3)
void word_attn_kernel(const int* __restrict__ word2news,
                      const int* __restrict__ word2news_len,
                      const float* __restrict__ table,
                      const float* __restrict__ in_w,
                      const float* __restrict__ in_b,
                      const float* __restrict__ out_w,
                      const float* __restrict__ out_b,
                      const u16* __restrict__ Kn16,
                      const u16* __restrict__ Vn16,
                      u16* __restrict__ we16)
{
    const int v0 = blockIdx.x * WPB;
    const int t = threadIdx.x;

    __shared__ int   rows[WPB][MM];
    __shared__ int   lenS[WPB];
    __shared__ float q[WPB][EE];
    __shared__ float qh[WPB][EE];
    __shared__ float attn[WPB][HH][MM];
    __shared__ float osh[WPB][EE];

    {
        const int w = t >> 5, m = t & 31;
        rows[w][m] = word2news[(size_t)(v0 + w) * MM + m];
        if (t < WPB) lenS[t] = word2news_len[v0 + t];
    }
    __syncthreads();

    {
        const int w = t >> 5, d0 = (t & 31) * 4;
        const int L = lenS[w];
        float4 a = {0.f, 0.f, 0.f, 0.f};
        #pragma unroll 4
        for (int m = 0; m < MM; ++m) {
            const float4 x = *(const float4*)&table[(size_t)rows[w][m] * EE + d0];
            if (m < L) { a.x += x.x; a.y += x.y; a.z += x.z; a.w += x.w; }
        }
        const float inv = (L > 0) ? 1.0f / (float)L : 0.0f;
        a.x *= inv; a.y *= inv; a.z *= inv; a.w *= inv;
        *(float4*)&q[w][d0] = a;
    }
    __syncthreads();

    {
        const int g = t >> 7, i = t & 127;
        const float* wr = in_w + (size_t)i * EE;
        float acc[4] = {0.f, 0.f, 0.f, 0.f};
        #pragma unroll 4
        for (int k = 0; k < EE; k += 4) {
            const float4 wv = *(const float4*)&wr[k];
            #pragma unroll
            for (int w4 = 0; w4 < 4; ++w4) {
                const float* qw = q[g * 4 + w4];
                acc[w4] += qw[k] * wv.x + qw[k + 1] * wv.y
                         + qw[k + 2] * wv.z + qw[k + 3] * wv.w;
            }
        }
        const float b = in_b[i];
        #pragma unroll
        for (int w4 = 0; w4 < 4; ++w4) qh[g * 4 + w4][i] = acc[w4] + b;
    }
    __syncthreads();

    {
        const int w = t >> 5, m = t & 31;
        const int L = lenS[w];
        float s[HH] = {-1e9f, -1e9f, -1e9f, -1e9f};
        if (m < L) {
            const uint4* kr = (const uint4*)(Kn16 + (size_t)rows[w][m] * EE);
            #pragma unroll 1
            for (int h = 0; h < HH; ++h) {
                float a = 0.f;
                #pragma unroll
                for (int k8 = 0; k8 < 4; ++k8) {
                    const uint4 u = kr[h * 4 + k8];
                    const float4 q0 = *(const float4*)&qh[w][h * 32 + k8 * 8];
                    const float4 q1 = *(const float4*)&qh[w][h * 32 + k8 * 8 + 4];
                    a += q0.x * bflo(u.x) + q0.y * bfhi(u.x)
                       + q0.z * bflo(u.y) + q0.w * bfhi(u.y)
                       + q1.x * bflo(u.z) + q1.y * bfhi(u.z)
                       + q1.z * bflo(u.w) + q1.w * bfhi(u.w);
                }
                s[h] = a * 0.17677669529663687f;
            }
        }
        #pragma unroll
        for (int h = 0; h < HH; ++h) {
            float mx = s[h];
            #pragma unroll
            for (int off = 16; off > 0; off >>= 1)
                mx = fmaxf(mx, __shfl_xor(mx, off, 32));
            const float ex = expf(s[h] - mx);
            float sum = ex;
            #pragma unroll
            for (int off = 16; off > 0; off >>= 1)
                sum += __shfl_xor(sum, off, 32);
            attn[w][h][m] = ex / sum;
        }
    }
    __syncthreads();

    {
        const int w = t >> 5, d0 = (t & 31) * 4;
        const int h = d0 >> 5;
        float4 a = {0.f, 0.f, 0.f, 0.f};
        #pragma unroll 4
        for (int m = 0; m < MM; ++m) {
            const float aw = attn[w][h][m];
            const u32* vr = (const u32*)(Vn16 + (size_t)rows[w][m] * EE + d0);
            const u32 u0 = vr[0], u1 = vr[1];
            a.x += aw * bflo(u0); a.y += aw * bfhi(u0);
            a.z += aw * bflo(u1); a.w += aw * bfhi(u1);
        }
        *(float4*)&osh[w][d0] = a;
    }
    __syncthreads();

    {
        const int g = t >> 7, i = t & 127;
        const float* wr = out_w + (size_t)i * EE;
        float acc[4] = {0.f, 0.f, 0.f, 0.f};
        #pragma unroll 4
        for (int k = 0; k < EE; k += 4) {
            const float4 wv = *(const float4*)&wr[k];
            #pragma unroll
            for (int w4 = 0; w4 < 4; ++w4) {
                const float* ow = osh[g * 4 + w4];
                acc[w4] += ow[k] * wv.x + ow[k + 1] * wv.y
                         + ow[k + 2] * wv.z + ow[k + 3] * wv.w;
            }
        }
        const float b = out_b[i];
        #pragma unroll
        for (int w4 = 0; w4 < 4; ++w4) {
            const int w = g * 4 + w4;
            we16[(size_t)(v0 + w) * EE + i] =
                (lenS[w] > 0) ? f2bf(acc[w4] + b) : (u16)0;
        }
    }
}

// ---------------------------------------------------------------------------
// Kernel B'' (R19): per-word attention, fully fused — Qn gives qh directly,
// Wn folds the out-projection into the attention-weighted sum. 3 barriers,
// 3 gather phases, direct we16 store. No in_w/out_w access at all.
// ---------------------------------------------------------------------------
__global__ __launch_bounds__(256, 3)
void word_attn_wn(const int* __restrict__ word2news,
                  const int* __restrict__ word2news_len,
                  const u16* __restrict__ Qn16,
                  const u16* __restrict__ Kn16,
                  const u16* __restrict__ Wn16,
                  u16* __restrict__ we16)
{
    const int v0 = blockIdx.x * WPB;
    const int t = threadIdx.x;

    __shared__ int   rows[WPB][MM];
    __shared__ int   lenS[WPB];
    __shared__ float qh[WPB][EE];
    __shared__ float attn[WPB][HH][MM];

    {
        const int w = t >> 5, m = t & 31;
        rows[w][m] = word2news[(size_t)(v0 + w) * MM + m];
        if (t < WPB) lenS[t] = word2news_len[v0 + t];
    }
    __syncthreads();

    // qh = mean of gathered Qn rows (bias included; exact — weights sum to 1)
    {
        const int w = t >> 5, d0 = (t & 31) * 4;
        const int L = lenS[w];
        float4 a = {0.f, 0.f, 0.f, 0.f};
        #pragma unroll 4
        for (int m = 0; m < MM; ++m) {
            const u32* qr = (const u32*)(Qn16 + (size_t)rows[w][m] * EE + d0);
            const u32 u0 = qr[0], u1 = qr[1];
            if (m < L) {
                a.x += bflo(u0); a.y += bfhi(u0);
                a.z += bflo(u1); a.w += bfhi(u1);
            }
        }
        const float inv = (L > 0) ? 1.0f / (float)L : 0.0f;
        a.x *= inv; a.y *= inv; a.z *= inv; a.w *= inv;
        *(float4*)&qh[w][d0] = a;
    }
    __syncthreads();

    // scores (gather Kn rows) + softmax over m; one head at a time.
    {
        const int w = t >> 5, m = t & 31;
        const int L = lenS[w];
        float s[HH] = {-1e9f, -1e9f, -1e9f, -1e9f};
        if (m < L) {
            const uint4* kr = (const uint4*)(Kn16 + (size_t)rows[w][m] * EE);
            #pragma unroll 1
            for (int h = 0; h < HH; ++h) {
                float a = 0.f;
                #pragma unroll
                for (int k8 = 0; k8 < 4; ++k8) {
                    const uint4 u = kr[h * 4 + k8];
                    const float4 q0 = *(const float4*)&qh[w][h * 32 + k8 * 8];
                    const float4 q1 = *(const float4*)&qh[w][h * 32 + k8 * 8 + 4];
                    a += q0.x * bflo(u.x) + q0.y * bfhi(u.x)
                       + q0.z * bflo(u.y) + q0.w * bfhi(u.y)
                       + q1.x * bflo(u.z) + q1.y * bfhi(u.z)
                       + q1.z * bflo(u.w) + q1.w * bfhi(u.w);
                }
                s[h] = a * 0.17677669529663687f;
            }
        }
        #pragma unroll
        for (int h = 0; h < HH; ++h) {
            float mx = s[h];
            #pragma unroll
            for (int off = 16; off > 0; off >>= 1)
                mx = fmaxf(mx, __shfl_xor(mx, off, 32));
            const float ex = expf(s[h] - mx);      // masked lanes underflow to 0
            float sum = ex;
            #pragma unroll
            for (int off = 16; off > 0; off >>= 1)
                sum += __shfl_xor(sum, off, 32);
            attn[w][h][m] = ex / sum;
        }
    }
    __syncthreads();

    // we = sum_m attn_m * Wn[rows[m]]  (out-proj + bias pre-folded into Wn;
    // attn==0 exactly for m>=len). Direct bf16 store; zero for len==0 words.
    {
        const int w = t >> 5, d0 = (t & 31) * 4;
        const int h = d0 >> 5;
        const int L = lenS[w];
        float4 a = {0.f, 0.f, 0.f, 0.f};
        #pragma unroll 4
        for (int m = 0; m < MM; ++m) {
            const float aw = attn[w][h][m];
            const u32* vr = (const u32*)(Wn16 + (size_t)rows[w][m] * EE + d0);
            const u32 u0 = vr[0], u1 = vr[1];
            a.x += aw * bflo(u0); a.y += aw * bfhi(u0);
            a.z += aw * bflo(u1); a.w += aw * bfhi(u1);
        }
        u32 lo = 0u, hi = 0u;
        if (L > 0) {
            lo = (u32)f2bf(a.x) | ((u32)f2bf(a.y) << 16);
            hi = (u32)f2bf(a.z) | ((u32)f2bf(a.w) << 16);
        }
        u32* dst = (u32*)(we16 + (size_t)(v0 + w) * EE + d0);
        dst[0] = lo; dst[1] = hi;
    }
}

// ---------------------------------------------------------------------------
// Kernel 2: implicit-GEMM conv — R16/R18 MEASURED OPTIMUM, unchanged.
// 512 threads / 4 docs; per-wave acc 4x4 f32x4 (64 AGPR), unroll-2 K-loop,
// (512,4) cap 128 == measured demand (64 arch + 64 AGPR, zero spill).
// ENVELOPE MAP: 256thr=242us, 512thr=209-217us, 1024thr=329us. Keep 512.
// ---------------------------------------------------------------------------
#define DSTRIDE 136              // u16 per doc row (16B-aligned, 68 words)
#define DOCSZ   (68 * DSTRIDE)   // u16 per doc (64 data rows + 4 zero rows)

template<int NSL, int SBASE, int NP>
__device__ __forceinline__ void conv_g2(const u16* __restrict__ lds,
                                        const u16* __restrict__ Bpack,
                                        const float* __restrict__ bk,
                                        int p, int nth, int l,
                                        float (&mxout)[4])
{
    f32x4 acc[4][4];
    #pragma unroll
    for (int mt = 0; mt < 4; ++mt)
        #pragma unroll
        for (int k = 0; k < 4; ++k)
            acc[mt][k] = (f32x4){0.f, 0.f, 0.f, 0.f};

    const int lm = l & 15;
    const int g  = l >> 4;
    const u16* bbase = Bpack + ((size_t)SBASE * 8 + nth * 4) * 512 + l * 8;
    const u16* abase = lds + (size_t)p * DOCSZ;

    #pragma unroll 2
    for (int s = 0; s < NSL; ++s) {
        const int j  = s >> 2;
        const int e0 = (s & 3) * 32;

        bf16x8 b[4];
        #pragma unroll
        for (int k = 0; k < 4; ++k)
            b[k] = *(const bf16x8*)(bbase + s * 4096 + k * 512);

        const u16* arow = abase + (lm + j) * DSTRIDE + e0 + g * 8;
        bf16x8 a[4];
        #pragma unroll
        for (int mt = 0; mt < 4; ++mt)
            a[mt] = *(const bf16x8*)(arow + mt * (16 * DSTRIDE));

        #pragma unroll
        for (int mt = 0; mt < 4; ++mt)
            #pragma unroll
            for (int k = 0; k < 4; ++k)
                acc[mt][k] = __builtin_amdgcn_mfma_f32_16x16x32_bf16(a[mt], b[k], acc[mt][k], 0, 0, 0);
    }

    #pragma unroll
    for (int k = 0; k < 4; ++k) {
        const int c = nth * 64 + k * 16 + lm;
        const float bias = bk[c];
        float mx = 0.0f;                     // relu output >= 0
        #pragma unroll
        for (int mt = 0; mt < 4; ++mt) {
            #pragma unroll
            for (int r = 0; r < 4; ++r) {
                const int pos = 16 * mt + g * 4 + r;
                const float y = fmaxf(acc[mt][k][r] + bias, 0.0f);
                if (pos < NP) mx = fmaxf(mx, y);
            }
        }
        mx = fmaxf(mx, __shfl_xor(mx, 16));
        mx = fmaxf(mx, __shfl_xor(mx, 32));
        mxout[k] = mx;
    }
}

__global__ __launch_bounds__(512, 4)
void news_kernel(const int* __restrict__ news_words,
                 const u16* __restrict__ we16,
                 const u16* __restrict__ Bpack,
                 const float* __restrict__ b3,
                 const float* __restrict__ b4,
                 const float* __restrict__ b5,
                 const float* __restrict__ fcw, const float* __restrict__ fcb,
                 float* __restrict__ out)
{
    const int n0 = blockIdx.x * 4;
    const int t = threadIdx.x;
    const int w = t >> 6, l = t & 63;
    const int p = w >> 1, nth = w & 1;

    __shared__ u16 lds[4 * DOCSZ];           // 73,984 B; feats alias after convs
    __shared__ int rows[4 * LL];

    if (t < 4 * LL) rows[t] = news_words[(size_t)n0 * LL + t];
    __syncthreads();

    {
        const uint4* weU = (const uint4*)we16;     // 16 uint4 per doc row
        uint4* ldsU = (uint4*)lds;                 // doc stride 1156 uint4
        for (int idx = t; idx < 4096; idx += 512) {
            const int d = idx >> 10, rem = idx & 1023;
            const int row = rem >> 4, c4 = rem & 15;
            ldsU[d * 1156 + row * 17 + c4] = weU[(size_t)rows[d * 64 + row] * 16 + c4];
        }
        if (t < 256) {                             // 4 docs x 4 pad rows x 16
            const int d = t >> 6, rem = t & 63;
            const int row = 64 + (rem >> 4), c4 = rem & 15;
            ldsU[d * 1156 + row * 17 + c4] = (uint4){0u, 0u, 0u, 0u};
        }
    }
    __syncthreads();

    float m3[4], m4[4], m5[4];
    conv_g2<12,  0, 62>(lds, Bpack, b3, p, nth, l, m3);
    conv_g2<16, 12, 61>(lds, Bpack, b4, p, nth, l, m4);
    conv_g2<20, 28, 60>(lds, Bpack, b5, p, nth, l, m5);
    __syncthreads();                          // docs dead beyond this point

    float* feats = (float*)lds;               // [4][384] aliases doc buffer
    if ((l >> 4) == 0) {
        const int lm = l & 15;
        #pragma unroll
        for (int k = 0; k < 4; ++k) {
            const int c = nth * 64 + k * 16 + lm;
            feats[p * 384 +   0 + c] = m3[k];
            feats[p * 384 + 128 + c] = m4[k];
            feats[p * 384 + 256 + c] = m5[k];
        }
    }
    __syncthreads();

    if (t < 128) {
        const float4* wr4 = (const float4*)(fcw + (size_t)t * (3 * CC));
        float a0 = fcb[t], a1 = a0, a2 = a0, a3 = a0;
        for (int f4 = 0; f4 < 96; ++f4) {
            const float4 wv = wr4[f4];
            const float4 x0 = *(const float4*)&feats[0 * 384 + f4 * 4];
            const float4 x1 = *(const float4*)&feats[1 * 384 + f4 * 4];
            const float4 x2 = *(const float4*)&feats[2 * 384 + f4 * 4];
            const float4 x3 = *(const float4*)&feats[3 * 384 + f4 * 4];
            a0 += x0.x * wv.x + x0.y * wv.y + x0.z * wv.z + x0.w * wv.w;
            a1 += x1.x * wv.x + x1.y * wv.y + x1.z * wv.z + x1.w * wv.w;
            a2 += x2.x * wv.x + x2.y * wv.y + x2.z * wv.z + x2.w * wv.w;
            a3 += x3.x * wv.x + x3.y * wv.y + x3.z * wv.z + x3.w * wv.w;
        }
        out[(size_t)(n0 + 0) * EE + t] = a0;
        out[(size_t)(n0 + 1) * EE + t] = a1;
        out[(size_t)(n0 + 2) * EE + t] = a2;
        out[(size_t)(n0 + 3) * EE + t] = a3;
    }
}

// ---------------------------------------------------------------------------
extern "C" void kernel_launch(void* const* d_in, const int* in_sizes, int n_in,
                              void* d_out, int out_size, void* d_ws, size_t ws_size,
                              hipStream_t stream)
{
    const int*   word2news     = (const int*)d_in[0];
    const int*   word2news_len = (const int*)d_in[1];
    const int*   news_words    = (const int*)d_in[2];
    const float* table         = (const float*)d_in[3];
    const float* in_w          = (const float*)d_in[4];
    const float* in_b          = (const float*)d_in[5];
    const float* out_w         = (const float*)d_in[6];
    const float* out_b         = (const float*)d_in[7];
    const float* w3            = (const float*)d_in[8];
    const float* b3            = (const float*)d_in[9];
    const float* w4            = (const float*)d_in[10];
    const float* b4            = (const float*)d_in[11];
    const float* w5            = (const float*)d_in[12];
    const float* b5            = (const float*)d_in[13];
    const float* fcw           = (const float*)d_in[14];
    const float* fcb           = (const float*)d_in[15];

    float* out = (float*)d_out;
    u16* base  = (u16*)d_ws;
    u16* we16  = base;                                   // 2,560,000 u16 (5.12 MB)
    u16* Bpack = base + 2560000;                         //   196,608 u16
    u16* Kn16  = base + 2756608;                         // 1,048,576 u16
    u16* Wn16  = base + 3805184;                         // 1,048,576 u16 (Vn slot)
    u16* Qn16  = base + 4853760;                         // 1,048,576 u16 (11.80 MB)
    const size_t need_qn = (size_t)(4853760 + 1048576) * 2;

    pack_weights<<<48, 256, 0, stream>>>(w3, w4, w5, Bpack);

    if (ws_size >= need_qn) {
        // Fused path (proven available in R17): Qn folds the query side,
        // Wn folds the out-projection.
        kvqw_proj_kernel<<<NN / 8, 384, 0, stream>>>(table, in_w, in_b,
                                                     out_w, out_b,
                                                     Qn16, Kn16, Wn16);
        word_attn_wn<<<V_WORDS / WPB, 256, 0, stream>>>(
            word2news, word2news_len, Qn16, Kn16, Wn16, we16);
    } else {
        kv_proj_kernel<<<NN / 8, 256, 0, stream>>>(table, in_w, in_b, Kn16, Wn16);
        word_attn_kernel<<<V_WORDS / WPB, 256, 0, stream>>>(
            word2news, word2news_len, table, in_w, in_b, out_w, out_b,
            Kn16, Wn16, we16);
    }

    news_kernel<<<NN / 4, 512, 0, stream>>>(
        news_words, we16, Bpack, b3, b4, b5, fcw, fcb, out);
}